// Round 1
// 599.785 us; speedup vs baseline: 1.0935x; 1.0935x over previous
//
#include <hip/hip_runtime.h>
#include <cstdint>

// Problem constants
#define TT 512   // KVLEN
#define CC 512   // C
#define HH 8     // heads
#define NN 64    // head dim
#define BQ 32    // BATCH*QLEN
#define NB 4     // BATCH

__device__ __forceinline__ float sigm(float x){ return 1.f/(1.f+__expf(-x)); }

__device__ __forceinline__ float wsum(float x){
  #pragma unroll
  for (int o=32;o;o>>=1) x += __shfl_xor(x, o, 64);
  return x;
}

// wave-uniform broadcast: register of lane `l` -> SGPR (VALU pipe, not LDS)
__device__ __forceinline__ float rlane(float x, int l){
  return __int_as_float(__builtin_amdgcn_readlane(__float_as_int(x), l));
}

// ---------------------------------------------------------------------------
// Batched wave64 row-sum, VALU-only (no LDS pipe, no barrier):
//   stages 1-4: DPP row_ror 1/2/4/8  -> every lane holds its 16-group sum
//   stage 5: v_permlane16_swap_b32 (a=b=x) -> pair-of-rows sums
//   stage 6: v_permlane32_swap_b32 (a=b=x) -> full 64-lane sum, all lanes
// Explicit v_mov before each permlane guarantees distinct registers; the
// mov/permlane loops are interleaved across NR rows so each permlane's
// source was written >=NR instructions earlier (hazard spacing).
// ---------------------------------------------------------------------------
template<int NR>
__device__ __forceinline__ void rowsum64_batch(float* x){
  #pragma unroll
  for (int i=0;i<NR;i++)
    x[i] += __int_as_float(__builtin_amdgcn_mov_dpp(__float_as_int(x[i]), 0x121, 0xf, 0xf, true));
  #pragma unroll
  for (int i=0;i<NR;i++)
    x[i] += __int_as_float(__builtin_amdgcn_mov_dpp(__float_as_int(x[i]), 0x122, 0xf, 0xf, true));
  #pragma unroll
  for (int i=0;i<NR;i++)
    x[i] += __int_as_float(__builtin_amdgcn_mov_dpp(__float_as_int(x[i]), 0x124, 0xf, 0xf, true));
  #pragma unroll
  for (int i=0;i<NR;i++)
    x[i] += __int_as_float(__builtin_amdgcn_mov_dpp(__float_as_int(x[i]), 0x128, 0xf, 0xf, true));
  float y[NR];
  #pragma unroll
  for (int i=0;i<NR;i++) asm("v_mov_b32 %0, %1" : "=v"(y[i]) : "v"(x[i]));
  #pragma unroll
  for (int i=0;i<NR;i++) asm("v_permlane16_swap_b32 %0, %1" : "+v"(x[i]), "+v"(y[i]));
  #pragma unroll
  for (int i=0;i<NR;i++) x[i] += y[i];
  #pragma unroll
  for (int i=0;i<NR;i++) asm("v_mov_b32 %0, %1" : "=v"(y[i]) : "v"(x[i]));
  #pragma unroll
  for (int i=0;i<NR;i++) asm("v_permlane32_swap_b32 %0, %1" : "+v"(x[i]), "+v"(y[i]));
  #pragma unroll
  for (int i=0;i<NR;i++) x[i] += y[i];
}

// ---------------------------------------------------------------------------
// k_prep: per-bq small dots (32 blocks): Qw[bq,32], Qa[bq,32], gh[bq,96],
// and xr row -> workspace.
// ---------------------------------------------------------------------------
__global__ __launch_bounds__(256) void k_prep(
  const float* __restrict__ q, const float* __restrict__ kv,
  const float* __restrict__ x_r, const float* __restrict__ x_w,
  const float* __restrict__ x_a, const float* __restrict__ x_g,
  const float* __restrict__ w1, const float* __restrict__ a1,
  const float* __restrict__ g1,
  float* __restrict__ Qw, float* __restrict__ Qa,
  float* __restrict__ ghw, float* __restrict__ xrw)
{
  int bq = blockIdx.x, b = bq >> 3, tid = threadIdx.x;
  int wave = tid >> 6, lane = tid & 63;
  __shared__ float qxw[CC], qxa[CC], sxg[CC];
  for (int c = tid; c < CC; c += 256){
    float qv = q[bq*CC + c];
    float kl = kv[((size_t)b*TT + (TT-1))*CC + c];
    xrw[bq*CC + c] = kl + (qv - kl)*x_r[c];
    sxg[c] = kl + (qv - kl)*x_g[c];
    qxw[c] = qv*x_w[c];
    qxa[c] = qv*x_a[c];
  }
  __syncthreads();
  for (int dot = wave; dot < 160; dot += 4){
    const float* buf; const float* W; int ld, dd;
    if (dot < 32)      { buf = qxw; W = w1; ld = 32; dd = dot; }
    else if (dot < 64) { buf = qxa; W = a1; ld = 32; dd = dot-32; }
    else               { buf = sxg; W = g1; ld = 96; dd = dot-64; }
    float s = 0.f;
    #pragma unroll
    for (int m = 0; m < 8; m++){
      int c = m*64 + lane;
      s = fmaf(buf[c], W[c*ld + dd], s);
    }
    s = wsum(s);
    if (lane == 0){
      if (dot < 32)      Qw[bq*32 + dd] = s;
      else if (dot < 64) Qa[bq*32 + dd] = s;
      else               ghw[bq*96 + dd] = sigm(s);
    }
  }
}

// ---------------------------------------------------------------------------
// k_rg: rrow[bq,co] = xr[bq,:]@Wr[:,co], grow[bq,co] = gh[bq,:]@g2[:,co]
// ---------------------------------------------------------------------------
__global__ __launch_bounds__(256) void k_rg(
  const float* __restrict__ xrw, const float* __restrict__ ghw,
  const float* __restrict__ Wr, const float* __restrict__ g2,
  float* __restrict__ rrow, float* __restrict__ grow)
{
  int bq = blockIdx.y; int co0 = blockIdx.x*64;
  int tid = threadIdx.x, tx = tid & 63, ty = tid >> 6;
  __shared__ float sxr[CC];
  __shared__ float sgh[96];
  __shared__ float red[4][64];
  sxr[tid]     = xrw[bq*CC + tid];
  sxr[tid+256] = xrw[bq*CC + tid + 256];
  if (tid < 96) sgh[tid] = ghw[bq*96 + tid];
  __syncthreads();
  float p = 0.f;
  for (int i = 0; i < 128; i++){
    int c = ty*128 + i;
    p = fmaf(sxr[c], Wr[(size_t)c*CC + co0 + tx], p);
  }
  red[ty][tx] = p;
  float pg = 0.f;
  for (int d = ty*24; d < ty*24 + 24; d++)
    pg = fmaf(sgh[d], g2[(size_t)d*CC + co0 + tx], pg);
  __syncthreads();
  if (ty == 0)
    rrow[bq*CC + co0 + tx] = (red[0][tx]+red[1][tx])+(red[2][tx]+red[3][tx]);
  __syncthreads();
  red[ty][tx] = pg;
  __syncthreads();
  if (ty == 0)
    grow[bq*CC + co0 + tx] = (red[0][tx]+red[1][tx])+(red[2][tx]+red[3][tx]);
}

// ---------------------------------------------------------------------------
// k_shift: elementwise token-shift mix: xk, xv.  float4, coalesced.
// ---------------------------------------------------------------------------
__global__ __launch_bounds__(256) void k_shift(
  const float* __restrict__ kv, const float* __restrict__ x_k,
  const float* __restrict__ x_v,
  float* __restrict__ xk, float* __restrict__ xv)
{
  int g = blockIdx.x*256 + threadIdx.x;      // float4 index, [0, 262144)
  int bt = g >> 7, t = bt & (TT-1), c4 = g & 127;
  const float4* kv4 = (const float4*)kv;
  float4 cur = kv4[g];
  float4 sh  = t ? kv4[g-128] : make_float4(0.f,0.f,0.f,0.f);
  float4 kc  = ((const float4*)x_k)[c4];
  float4 vc  = ((const float4*)x_v)[c4];
  float4 ok, ov;
  ok.x = cur.x + (sh.x-cur.x)*kc.x; ov.x = cur.x + (sh.x-cur.x)*vc.x;
  ok.y = cur.y + (sh.y-cur.y)*kc.y; ov.y = cur.y + (sh.y-cur.y)*vc.y;
  ok.z = cur.z + (sh.z-cur.z)*kc.z; ov.z = cur.z + (sh.z-cur.z)*vc.z;
  ok.w = cur.w + (sh.w-cur.w)*kc.w; ov.w = cur.w + (sh.w-cur.w)*vc.w;
  ((float4*)xk)[g] = ok;
  ((float4*)xv)[g] = ov;
}

// ---------------------------------------------------------------------------
// k_pgemm: three [2048x512]@[512x32] products (Pw, Pa, HV), tiled.
// ---------------------------------------------------------------------------
__global__ __launch_bounds__(256) void k_pgemm(
  const float* __restrict__ kv, const float* __restrict__ xv,
  const float* __restrict__ x_w, const float* __restrict__ x_a,
  const float* __restrict__ w1, const float* __restrict__ a1,
  const float* __restrict__ v1,
  float* __restrict__ Pw, float* __restrict__ Pa, float* __restrict__ HV)
{
  int mat = blockIdx.y;
  int r0 = blockIdx.x * 64;
  const float* A = (mat == 2) ? xv : kv;
  const float* B = (mat == 0) ? w1 : (mat == 1) ? a1 : v1;
  float* O       = (mat == 0) ? Pw : (mat == 1) ? Pa : HV;
  int tid = threadIdx.x;
  __shared__ float As[32][65];
  __shared__ float Bs[32][32];
  __shared__ float scl[CC];
  for (int c = tid; c < CC; c += 256)
    scl[c] = (mat == 0) ? (1.f - x_w[c]) : (mat == 1) ? (1.f - x_a[c]) : 1.f;
  __syncthreads();
  int tx = tid & 31, ty = tid >> 5;
  float acc[8];
  #pragma unroll
  for (int i = 0; i < 8; i++) acc[i] = 0.f;
  for (int k0 = 0; k0 < 512; k0 += 32){
    #pragma unroll
    for (int p = 0; p < 8; p++){
      int e = tid + p*256;
      int kk2 = e & 31, r = e >> 5;
      As[kk2][r] = A[(size_t)(r0+r)*512 + k0 + kk2] * scl[k0 + kk2];
    }
    #pragma unroll
    for (int p = 0; p < 4; p++){
      int e = tid + p*256;
      int n = e & 31, kk2 = e >> 5;
      Bs[kk2][n] = B[(size_t)(k0+kk2)*32 + n];
    }
    __syncthreads();
    #pragma unroll
    for (int kk2 = 0; kk2 < 32; kk2++){
      float bb = Bs[kk2][tx];
      #pragma unroll
      for (int i = 0; i < 8; i++)
        acc[i] = fmaf(As[kk2][ty*8 + i], bb, acc[i]);
    }
    __syncthreads();
  }
  #pragma unroll
  for (int i = 0; i < 8; i++)
    O[(size_t)(r0 + ty*8 + i)*32 + tx] = acc[i];
}

// ---------------------------------------------------------------------------
// k_sv: sv[bt,c] = sigm(v0[c] + HV[bt,:]@v2[:,c])
// ---------------------------------------------------------------------------
__global__ __launch_bounds__(256) void k_sv(
  const float* __restrict__ HV, const float* __restrict__ v2,
  const float* __restrict__ v0, float* __restrict__ svv)
{
  int bt = blockIdx.x, tid = threadIdx.x;
  __shared__ float hv[32];
  if (tid < 32) hv[tid] = HV[bt*32 + tid];
  __syncthreads();
  for (int c = tid; c < CC; c += 256){
    float s = 0.f;
    #pragma unroll
    for (int d = 0; d < 32; d++) s = fmaf(hv[d], v2[d*CC + c], s);
    svv[(size_t)bt*CC + c] = sigm(v0[c] + s);
  }
}

// ---------------------------------------------------------------------------
// Tiled fp32 GEMM: C[2048x512] = A[2048x512] @ W[512x512]. 64x64 tile.
// ---------------------------------------------------------------------------
__global__ __launch_bounds__(256) void gemm_2048_512(
  const float* __restrict__ A, const float* __restrict__ W, float* __restrict__ Co)
{
  __shared__ float As[32][68];
  __shared__ float Bs[32][64];
  int tid = threadIdx.x;
  int tx = tid & 15, ty = tid >> 4;
  int m0 = blockIdx.y*64, n0 = blockIdx.x*64;
  float acc[4][4];
  #pragma unroll
  for (int i=0;i<4;i++)
    #pragma unroll
    for (int j=0;j<4;j++) acc[i][j]=0.f;

  for (int k0 = 0; k0 < 512; k0 += 32){
    #pragma unroll
    for (int i = 0; i < 8; i++){
      int e = tid + i*256;
      int kk = e & 31, m = e >> 5;
      As[kk][m] = A[(size_t)(m0+m)*512 + k0 + kk];
    }
    #pragma unroll
    for (int i = 0; i < 8; i++){
      int e = tid + i*256;
      int n = e & 63, kk = e >> 6;
      Bs[kk][n] = W[(size_t)(k0+kk)*512 + n0 + n];
    }
    __syncthreads();
    #pragma unroll
    for (int kk = 0; kk < 32; kk++){
      float a4[4], b4[4];
      #pragma unroll
      for (int i=0;i<4;i++) a4[i] = As[kk][ty*4+i];
      #pragma unroll
      for (int j=0;j<4;j++) b4[j] = Bs[kk][tx*4+j];
      #pragma unroll
      for (int i=0;i<4;i++)
        #pragma unroll
        for (int j=0;j<4;j++) acc[i][j] += a4[i]*b4[j];
    }
    __syncthreads();
  }
  #pragma unroll
  for (int i=0;i<4;i++)
    #pragma unroll
    for (int j=0;j<4;j++)
      Co[(size_t)(m0+ty*4+i)*512 + n0 + tx*4 + j] = acc[i][j];
}

// ---------------------------------------------------------------------------
// K1b: kk = normalize_per_head(k * k_k)
// ---------------------------------------------------------------------------
__global__ __launch_bounds__(512) void k_kk(
  const float* __restrict__ kg, const float* __restrict__ k_k,
  float* __restrict__ kkg)
{
  int bt = blockIdx.x, tid = threadIdx.x;
  float v = kg[(size_t)bt*CC + tid]*k_k[tid];
  float ss = wsum(v*v);
  float nrm = fmaxf(sqrtf(ss), 1e-12f);
  kkg[(size_t)bt*CC + tid] = v/nrm;
}

// ---------------------------------------------------------------------------
// K2: per (bq,t,c): decay w, k_final, b_vec = kk*a.  4 rows per block.
// ---------------------------------------------------------------------------
__global__ __launch_bounds__(256) void k_wkb(
  const float* __restrict__ Pw, const float* __restrict__ Pa,
  const float* __restrict__ Qw, const float* __restrict__ Qa,
  const float* __restrict__ w2, const float* __restrict__ a2,
  const float* __restrict__ w0, const float* __restrict__ a0,
  const float* __restrict__ k_a, const float* __restrict__ kg,
  const float* __restrict__ kkg,
  float* __restrict__ wS, float* __restrict__ kS, float* __restrict__ bS)
{
  int bqt0 = blockIdx.x*4;           // 4 consecutive t within one bq
  int bq = bqt0 >> 9, t0 = bqt0 & (TT-1), b = bq >> 3;
  int tid = threadIdx.x;
  __shared__ float sth[4][32], sal[4][32];
  {
    int g = (tid >> 5) & 3, d = tid & 31;
    int pidx = ((b << 9) | (t0 + g))*32 + d;
    if (tid < 128) sth[g][d] = tanhf(Pw[pidx] + Qw[bq*32 + d]);
    else           sal[g][d] = Pa[pidx] + Qa[bq*32 + d];
  }
  __syncthreads();
  #pragma unroll
  for (int cc = 0; cc < 2; cc++){
    int c = tid + cc*256;
    float wreg[32], areg[32];
    #pragma unroll
    for (int d = 0; d < 32; d++){ wreg[d] = w2[d*CC + c]; areg[d] = a2[d*CC + c]; }
    float w0c = w0[c], a0c = a0[c], kac = k_a[c];
    #pragma unroll
    for (int g = 0; g < 4; g++){
      float wa = 0.f, aa = 0.f;
      #pragma unroll
      for (int d = 0; d < 32; d++){
        wa = fmaf(sth[g][d], wreg[d], wa);
        aa = fmaf(sal[g][d], areg[d], aa);
      }
      float a_sig = sigm(a0c + aa);
      float wdec  = __expf(-0.60653066f * sigm(w0c + wa));
      size_t bt = (size_t)((b << 9) | (t0 + g));
      size_t o  = (size_t)(bqt0 + g)*CC + c;
      float kvv = kg[bt*CC + c];
      float kkv = kkg[bt*CC + c];
      wS[o] = wdec;
      kS[o] = kvv*(1.f + (a_sig - 1.f)*kac);
      bS[o] = kkv*a_sig;
    }
  }
}

// ---------------------------------------------------------------------------
// K3: scan, row-split / barrier-free.
// 8 waves per (bq,h); wave w owns ROWS [8w, 8w+8), lane = COLUMN j.
// Per step, w_j/k_j/b_j/a'_j are lane-local coalesced loads (the bqt-major
// [bqt][c] layouts of wS/kS/bS/kkg are already j-contiguous per (h,t)).
// sa_i = sum_j S[i,j]*a'_j is a wave-local 64-lane reduction done entirely
// on the VALU pipe (DPP row_ror tree + permlane16/32_swap) -> the per-step
// s_barrier + psa LDS round trip of the previous version is GONE; the 512
// step loop contains zero LDS ops and zero barriers.  8 symmetric waves
// (2/SIMD) provide TLP to hide load + cross-lane latencies.
// Register pipeline 3-deep on all 7 input streams.
// ---------------------------------------------------------------------------
__global__ __launch_bounds__(512, 1) void k_scan(
  const float* __restrict__ wv, const float* __restrict__ kf,
  const float* __restrict__ bv, const float* __restrict__ kkg,
  const float* __restrict__ vpre, const float* __restrict__ svv,
  const float* __restrict__ vfirst,
  const float* __restrict__ rrow, const float* __restrict__ grow,
  const float* __restrict__ r_k, const float* __restrict__ ln_w,
  const float* __restrict__ ln_b, float* __restrict__ xo)
{
  __shared__ float pout[64];
  int blk = blockIdx.x; int bq = blk >> 3, h = blk & 7, b = bq >> 3;
  int tid = threadIdx.x; int wave = tid >> 6; int lane = tid & 63;
  int i0 = wave << 3;                    // first row owned by this wave
  size_t cb_bq = (size_t)bq*TT*CC + h*NN;
  size_t cb_b  = (size_t)b*TT*CC + h*NN;

  // per-column streams (lane = j), stride CC per step
  const float* pw = wv  + cb_bq + lane;
  const float* pk = kf  + cb_bq + lane;
  const float* pb = bv  + cb_bq + lane;
  const float* pa = kkg + cb_b + CC + lane;      // a'_t = kk[t+1] (batch)
  // v streams: row c = h*64 + i0 + (lane&7); lanes 0..7 carry the 8 rows
  int vrow = i0 + (lane & 7);
  const float* pvp = vpre   + cb_b  + vrow;
  const float* psv = svv    + cb_b  + vrow;
  const float* pvf = vfirst + cb_bq + vrow;

  float st[8], sa[8];
  #pragma unroll
  for (int i = 0; i < 8; i++){ st[i] = 0.f; sa[i] = 0.f; }

  // 3-deep register pipeline
  float cw0 = pw[0],  cw1 = pw[CC],  cw2 = pw[2*CC];
  float ck0 = pk[0],  ck1 = pk[CC],  ck2 = pk[2*CC];
  float cb0 = pb[0],  cb1 = pb[CC],  cb2 = pb[2*CC];
  float ca0 = pa[0],  ca1 = pa[CC],  ca2 = pa[2*CC];
  float vp0 = pvp[0], vp1 = pvp[CC], vp2 = pvp[2*CC];
  float sv0 = psv[0], sv1 = psv[CC], sv2 = psv[2*CC];
  float vf0 = pvf[0], vf1 = pvf[CC], vf2 = pvf[2*CC];

  #pragma unroll 3
  for (int t = 0; t < TT; t++){
    float wj = cw0, kj = ck0, bj = cb0, aj = ca0;
    float vl = vp0 + (vf0 - vp0)*sv0;            // v_t for row i0+(lane&7)
    // rotate pipeline; issue loads of step t+3
    cw0=cw1; cw1=cw2; ck0=ck1; ck1=ck2; cb0=cb1; cb1=cb2; ca0=ca1; ca1=ca2;
    vp0=vp1; vp1=vp2; sv0=sv1; sv1=sv2; vf0=vf1; vf1=vf2;
    {
      int tp = t+3; tp = (tp > TT-1) ? TT-1 : tp;
      int ta = t+3; ta = (ta > TT-2) ? TT-2 : ta;   // a' reads kk[ta+1]
      size_t op = (size_t)tp*CC, oa = (size_t)ta*CC;
      cw2 = pw[op]; ck2 = pk[op]; cb2 = pb[op]; ca2 = pa[oa];
      vp2 = pvp[op]; sv2 = psv[op]; vf2 = pvf[op];
    }
    // state update: S[i,j] = S[i,j]*w_j - sa_i*b_j + v_i*k_j
    // (sa holds +sum(S*kk_t); scan's a = -kk so negate via src modifier)
    #pragma unroll
    for (int il = 0; il < 8; il++){
      float vi = rlane(vl, il);                   // v for row i0+il (uniform)
      st[il] = fmaf(st[il], wj, fmaf(-sa[il], bj, vi*kj));
      sa[il] = st[il]*aj;                         // partial for next step's sa
    }
    rowsum64_batch<8>(sa);                        // VALU-only, broadcast
  }

  // epilogue: out_i = sum_j S[i,j] r_j
  {
    float rj = rrow[(size_t)bq*CC + h*NN + lane];
    float o[8];
    #pragma unroll
    for (int il = 0; il < 8; il++) o[il] = st[il]*rj;
    rowsum64_batch<8>(o);
    float po = 0.f;
    #pragma unroll
    for (int il = 0; il < 8; il++) po = (lane == il) ? o[il] : po;
    if (lane < 8) pout[i0 + lane] = po;
  }
  __syncthreads();
  if (wave == 0){
    float out = pout[lane];
    float mean = wsum(out) * (1.f/NN);
    float dv = out - mean;
    float var = wsum(dv*dv) * (1.f/NN);
    float yn = dv * rsqrtf(var + 6.4e-4f);   // GN_EPS = 1e-5*64
    int c = h*NN + lane;
    float y2 = yn * ln_w[c] + ln_b[c];
    float kl = kf[cb_bq + (size_t)(TT-1)*CC + lane];
    float rl = rrow[(size_t)bq*CC + c];
    float rk = wsum(rl*kl*r_k[c]);
    float vp_ = vpre  [cb_b  + (size_t)(TT-1)*CC + lane];
    float sv_ = svv   [cb_b  + (size_t)(TT-1)*CC + lane];
    float vf_ = vfirst[cb_bq + (size_t)(TT-1)*CC + lane];
    float v_i = vp_ + (vf_ - vp_)*sv_;       // v_{T-1} for row `lane`
    float res = (y2 + rk*v_i) * grow[(size_t)bq*CC + c];
    xo[bq*CC + c] = res;
  }
}

// ---------------------------------------------------------------------------
// K4: out[bq,co] = xo[bq,:] @ Wo[:,co]
// ---------------------------------------------------------------------------
__global__ __launch_bounds__(256) void k_out(
  const float* __restrict__ xo, const float* __restrict__ Wo,
  float* __restrict__ outp)
{
  int bq = blockIdx.y; int co0 = blockIdx.x*64;
  int tid = threadIdx.x, tx = tid & 63, ty = tid >> 6;
  __shared__ float row[CC];
  __shared__ float red[4][64];
  row[tid]     = xo[bq*CC + tid];
  row[tid+256] = xo[bq*CC + tid + 256];
  __syncthreads();
  float p = 0.f;
  for (int i = 0; i < 128; i++){
    int c = ty*128 + i;
    p = fmaf(row[c], Wo[(size_t)c*CC + co0 + tx], p);
  }
  red[ty][tx] = p;
  __syncthreads();
  if (ty == 0)
    outp[bq*CC + co0 + tx] = (red[0][tx]+red[1][tx])+(red[2][tx]+red[3][tx]);
}

// ---------------------------------------------------------------------------
extern "C" void kernel_launch(void* const* d_in, const int* in_sizes, int n_in,
                              void* d_out, int out_size, void* d_ws, size_t ws_size,
                              hipStream_t stream)
{
  const float* q   = (const float*)d_in[0];
  const float* kv  = (const float*)d_in[1];
  const float* vf  = (const float*)d_in[2];
  const float* x_r = (const float*)d_in[3];
  const float* x_w = (const float*)d_in[4];
  const float* x_k = (const float*)d_in[5];
  const float* x_v = (const float*)d_in[6];
  const float* x_a = (const float*)d_in[7];
  const float* x_g = (const float*)d_in[8];
  const float* w0  = (const float*)d_in[9];
  const float* w1  = (const float*)d_in[10];
  const float* w2  = (const float*)d_in[11];
  const float* a0  = (const float*)d_in[12];
  const float* a1  = (const float*)d_in[13];
  const float* a2  = (const float*)d_in[14];
  const float* v0  = (const float*)d_in[15];
  const float* v1  = (const float*)d_in[16];
  const float* v2  = (const float*)d_in[17];
  const float* g1  = (const float*)d_in[18];
  const float* g2  = (const float*)d_in[19];
  const float* k_k = (const float*)d_in[20];
  const float* k_a = (const float*)d_in[21];
  const float* r_k = (const float*)d_in[22];
  const float* Wr  = (const float*)d_in[23];
  const float* Wk  = (const float*)d_in[24];
  const float* Wv  = (const float*)d_in[25];
  const float* Wo  = (const float*)d_in[26];
  const float* lnw = (const float*)d_in[27];
  const float* lnb = (const float*)d_in[28];
  float* outp = (float*)d_out;
  float* ws = (float*)d_ws;

  // workspace layout (floats)
  float* xk = ws + 0;         // 4*512*512
  float* xv = ws + 1048576;
  float* kg = ws + 2097152;   // k
  float* vp = ws + 3145728;   // v_pre
  float* sv = ws + 4194304;   // sigmoid lerp factor
  float* kk = ws + 5242880;   // normalized kk
  float* Pw = ws + 6291456;   // 4*512*32
  float* Pa = ws + 6356992;
  float* Qw = ws + 6422528;   // 32*32
  float* Qa = ws + 6423552;
  float* HV = ws + 6424576;   // 4*512*32
  float* rr = ws + 7473152;   // 32*512
  float* gr = ws + 7489536;
  float* xo = ws + 7505920;
  float* wS = ws + 7522304;   // 32*512*512 decay
  float* kS = ws + 15910912;  // k_final
  float* bS = ws + 24299520;  // kk*a
  float* xrw = ws + 32688128; // 32*512
  float* ghw = ws + 32704512; // 32*96

  // v_first passthrough (tuple output #2)
  hipMemcpyAsync(outp + BQ*CC, vf,
                 (size_t)BQ*TT*CC*sizeof(float), hipMemcpyDeviceToDevice, stream);

  k_prep<<<32, 256, 0, stream>>>(q, kv, x_r, x_w, x_a, x_g, w1, a1, g1,
                                 Qw, Qa, ghw, xrw);
  k_rg<<<dim3(8, 32), 256, 0, stream>>>(xrw, ghw, Wr, g2, rr, gr);
  k_shift<<<1024, 256, 0, stream>>>(kv, x_k, x_v, xk, xv);
  gemm_2048_512<<<dim3(8, 32), 256, 0, stream>>>(xk, Wk, kg);
  gemm_2048_512<<<dim3(8, 32), 256, 0, stream>>>(xv, Wv, vp);
  k_pgemm<<<dim3(32, 3), 256, 0, stream>>>(kv, xv, x_w, x_a, w1, a1, v1,
                                           Pw, Pa, HV);
  k_sv<<<NB*TT, 256, 0, stream>>>(HV, v2, v0, sv);
  k_kk<<<NB*TT, 512, 0, stream>>>(kg, k_k, kk);
  k_wkb<<<BQ*TT/4, 256, 0, stream>>>(Pw, Pa, Qw, Qa, w2, a2, w0, a0, k_a,
                                     kg, kk, wS, kS, bS);
  k_scan<<<BQ*HH, 512, 0, stream>>>(wS, kS, bS, kk, vp, sv, vf, rr, gr, r_k,
                                    lnw, lnb, xo);
  k_out<<<dim3(8, 32), 256, 0, stream>>>(xo, Wo, outp);
}

// Round 2
// 408.232 us; speedup vs baseline: 1.6066x; 1.4692x over previous
//
#include <hip/hip_runtime.h>
#include <cstdint>

// Problem constants
#define TT 512   // KVLEN
#define CC 512   // C
#define HH 8     // heads
#define NN 64    // head dim
#define BQ 32    // BATCH*QLEN
#define NB 4     // BATCH

__device__ __forceinline__ float sigm(float x){ return 1.f/(1.f+__expf(-x)); }

__device__ __forceinline__ float wsum(float x){
  #pragma unroll
  for (int o=32;o;o>>=1) x += __shfl_xor(x, o, 64);
  return x;
}

// ---------------------------------------------------------------------------
// Batched wave64 row-sum, VALU-only (no LDS pipe, no barrier):
//   stages 1-4: DPP row_ror 1/2/4/8  -> every lane holds its 16-group sum
//   stage 5: v_permlane16_swap_b32 (a=b=x) -> pair-of-rows sums
//   stage 6: v_permlane32_swap_b32 (a=b=x) -> full 64-lane sum, all lanes
// ---------------------------------------------------------------------------
template<int NR>
__device__ __forceinline__ void rowsum64_batch(float* x){
  #pragma unroll
  for (int i=0;i<NR;i++)
    x[i] += __int_as_float(__builtin_amdgcn_mov_dpp(__float_as_int(x[i]), 0x121, 0xf, 0xf, true));
  #pragma unroll
  for (int i=0;i<NR;i++)
    x[i] += __int_as_float(__builtin_amdgcn_mov_dpp(__float_as_int(x[i]), 0x122, 0xf, 0xf, true));
  #pragma unroll
  for (int i=0;i<NR;i++)
    x[i] += __int_as_float(__builtin_amdgcn_mov_dpp(__float_as_int(x[i]), 0x124, 0xf, 0xf, true));
  #pragma unroll
  for (int i=0;i<NR;i++)
    x[i] += __int_as_float(__builtin_amdgcn_mov_dpp(__float_as_int(x[i]), 0x128, 0xf, 0xf, true));
  float y[NR];
  #pragma unroll
  for (int i=0;i<NR;i++) asm("v_mov_b32 %0, %1" : "=v"(y[i]) : "v"(x[i]));
  #pragma unroll
  for (int i=0;i<NR;i++) asm("v_permlane16_swap_b32 %0, %1" : "+v"(x[i]), "+v"(y[i]));
  #pragma unroll
  for (int i=0;i<NR;i++) x[i] += y[i];
  #pragma unroll
  for (int i=0;i<NR;i++) asm("v_mov_b32 %0, %1" : "=v"(y[i]) : "v"(x[i]));
  #pragma unroll
  for (int i=0;i<NR;i++) asm("v_permlane32_swap_b32 %0, %1" : "+v"(x[i]), "+v"(y[i]));
  #pragma unroll
  for (int i=0;i<NR;i++) x[i] += y[i];
}

// ---------------------------------------------------------------------------
// k_prep: per-bq small dots (32 blocks): Qw[bq,32], Qa[bq,32], gh[bq,96],
// and xr row -> workspace.
// ---------------------------------------------------------------------------
__global__ __launch_bounds__(256) void k_prep(
  const float* __restrict__ q, const float* __restrict__ kv,
  const float* __restrict__ x_r, const float* __restrict__ x_w,
  const float* __restrict__ x_a, const float* __restrict__ x_g,
  const float* __restrict__ w1, const float* __restrict__ a1,
  const float* __restrict__ g1,
  float* __restrict__ Qw, float* __restrict__ Qa,
  float* __restrict__ ghw, float* __restrict__ xrw)
{
  int bq = blockIdx.x, b = bq >> 3, tid = threadIdx.x;
  int wave = tid >> 6, lane = tid & 63;
  __shared__ float qxw[CC], qxa[CC], sxg[CC];
  for (int c = tid; c < CC; c += 256){
    float qv = q[bq*CC + c];
    float kl = kv[((size_t)b*TT + (TT-1))*CC + c];
    xrw[bq*CC + c] = kl + (qv - kl)*x_r[c];
    sxg[c] = kl + (qv - kl)*x_g[c];
    qxw[c] = qv*x_w[c];
    qxa[c] = qv*x_a[c];
  }
  __syncthreads();
  for (int dot = wave; dot < 160; dot += 4){
    const float* buf; const float* W; int ld, dd;
    if (dot < 32)      { buf = qxw; W = w1; ld = 32; dd = dot; }
    else if (dot < 64) { buf = qxa; W = a1; ld = 32; dd = dot-32; }
    else               { buf = sxg; W = g1; ld = 96; dd = dot-64; }
    float s = 0.f;
    #pragma unroll
    for (int m = 0; m < 8; m++){
      int c = m*64 + lane;
      s = fmaf(buf[c], W[c*ld + dd], s);
    }
    s = wsum(s);
    if (lane == 0){
      if (dot < 32)      Qw[bq*32 + dd] = s;
      else if (dot < 64) Qa[bq*32 + dd] = s;
      else               ghw[bq*96 + dd] = sigm(s);
    }
  }
}

// ---------------------------------------------------------------------------
// k_rg: rrow[bq,co] = xr[bq,:]@Wr[:,co], grow[bq,co] = gh[bq,:]@g2[:,co]
// ---------------------------------------------------------------------------
__global__ __launch_bounds__(256) void k_rg(
  const float* __restrict__ xrw, const float* __restrict__ ghw,
  const float* __restrict__ Wr, const float* __restrict__ g2,
  float* __restrict__ rrow, float* __restrict__ grow)
{
  int bq = blockIdx.y; int co0 = blockIdx.x*64;
  int tid = threadIdx.x, tx = tid & 63, ty = tid >> 6;
  __shared__ float sxr[CC];
  __shared__ float sgh[96];
  __shared__ float red[4][64];
  sxr[tid]     = xrw[bq*CC + tid];
  sxr[tid+256] = xrw[bq*CC + tid + 256];
  if (tid < 96) sgh[tid] = ghw[bq*96 + tid];
  __syncthreads();
  float p = 0.f;
  for (int i = 0; i < 128; i++){
    int c = ty*128 + i;
    p = fmaf(sxr[c], Wr[(size_t)c*CC + co0 + tx], p);
  }
  red[ty][tx] = p;
  float pg = 0.f;
  for (int d = ty*24; d < ty*24 + 24; d++)
    pg = fmaf(sgh[d], g2[(size_t)d*CC + co0 + tx], pg);
  __syncthreads();
  if (ty == 0)
    rrow[bq*CC + co0 + tx] = (red[0][tx]+red[1][tx])+(red[2][tx]+red[3][tx]);
  __syncthreads();
  red[ty][tx] = pg;
  __syncthreads();
  if (ty == 0)
    grow[bq*CC + co0 + tx] = (red[0][tx]+red[1][tx])+(red[2][tx]+red[3][tx]);
}

// ---------------------------------------------------------------------------
// k_shift: elementwise token-shift mix: xk, xv.  float4, coalesced.
// ---------------------------------------------------------------------------
__global__ __launch_bounds__(256) void k_shift(
  const float* __restrict__ kv, const float* __restrict__ x_k,
  const float* __restrict__ x_v,
  float* __restrict__ xk, float* __restrict__ xv)
{
  int g = blockIdx.x*256 + threadIdx.x;      // float4 index, [0, 262144)
  int bt = g >> 7, t = bt & (TT-1), c4 = g & 127;
  const float4* kv4 = (const float4*)kv;
  float4 cur = kv4[g];
  float4 sh  = t ? kv4[g-128] : make_float4(0.f,0.f,0.f,0.f);
  float4 kc  = ((const float4*)x_k)[c4];
  float4 vc  = ((const float4*)x_v)[c4];
  float4 ok, ov;
  ok.x = cur.x + (sh.x-cur.x)*kc.x; ov.x = cur.x + (sh.x-cur.x)*vc.x;
  ok.y = cur.y + (sh.y-cur.y)*kc.y; ov.y = cur.y + (sh.y-cur.y)*vc.y;
  ok.z = cur.z + (sh.z-cur.z)*kc.z; ov.z = cur.z + (sh.z-cur.z)*vc.z;
  ok.w = cur.w + (sh.w-cur.w)*kc.w; ov.w = cur.w + (sh.w-cur.w)*vc.w;
  ((float4*)xk)[g] = ok;
  ((float4*)xv)[g] = ov;
}

// ---------------------------------------------------------------------------
// k_pgemm: three [2048x512]@[512x32] products (Pw, Pa, HV), tiled.
// ---------------------------------------------------------------------------
__global__ __launch_bounds__(256) void k_pgemm(
  const float* __restrict__ kv, const float* __restrict__ xv,
  const float* __restrict__ x_w, const float* __restrict__ x_a,
  const float* __restrict__ w1, const float* __restrict__ a1,
  const float* __restrict__ v1,
  float* __restrict__ Pw, float* __restrict__ Pa, float* __restrict__ HV)
{
  int mat = blockIdx.y;
  int r0 = blockIdx.x * 64;
  const float* A = (mat == 2) ? xv : kv;
  const float* B = (mat == 0) ? w1 : (mat == 1) ? a1 : v1;
  float* O       = (mat == 0) ? Pw : (mat == 1) ? Pa : HV;
  int tid = threadIdx.x;
  __shared__ float As[32][65];
  __shared__ float Bs[32][32];
  __shared__ float scl[CC];
  for (int c = tid; c < CC; c += 256)
    scl[c] = (mat == 0) ? (1.f - x_w[c]) : (mat == 1) ? (1.f - x_a[c]) : 1.f;
  __syncthreads();
  int tx = tid & 31, ty = tid >> 5;
  float acc[8];
  #pragma unroll
  for (int i = 0; i < 8; i++) acc[i] = 0.f;
  for (int k0 = 0; k0 < 512; k0 += 32){
    #pragma unroll
    for (int p = 0; p < 8; p++){
      int e = tid + p*256;
      int kk2 = e & 31, r = e >> 5;
      As[kk2][r] = A[(size_t)(r0+r)*512 + k0 + kk2] * scl[k0 + kk2];
    }
    #pragma unroll
    for (int p = 0; p < 4; p++){
      int e = tid + p*256;
      int n = e & 31, kk2 = e >> 5;
      Bs[kk2][n] = B[(size_t)(k0+kk2)*32 + n];
    }
    __syncthreads();
    #pragma unroll
    for (int kk2 = 0; kk2 < 32; kk2++){
      float bb = Bs[kk2][tx];
      #pragma unroll
      for (int i = 0; i < 8; i++)
        acc[i] = fmaf(As[kk2][ty*8 + i], bb, acc[i]);
    }
    __syncthreads();
  }
  #pragma unroll
  for (int i = 0; i < 8; i++)
    O[(size_t)(r0 + ty*8 + i)*32 + tx] = acc[i];
}

// ---------------------------------------------------------------------------
// k_sv: sv[bt,c] = sigm(v0[c] + HV[bt,:]@v2[:,c])
// ---------------------------------------------------------------------------
__global__ __launch_bounds__(256) void k_sv(
  const float* __restrict__ HV, const float* __restrict__ v2,
  const float* __restrict__ v0, float* __restrict__ svv)
{
  int bt = blockIdx.x, tid = threadIdx.x;
  __shared__ float hv[32];
  if (tid < 32) hv[tid] = HV[bt*32 + tid];
  __syncthreads();
  for (int c = tid; c < CC; c += 256){
    float s = 0.f;
    #pragma unroll
    for (int d = 0; d < 32; d++) s = fmaf(hv[d], v2[d*CC + c], s);
    svv[(size_t)bt*CC + c] = sigm(v0[c] + s);
  }
}

// ---------------------------------------------------------------------------
// Tiled fp32 GEMM: C[2048x512] = A[2048x512] @ W[512x512]. 64x64 tile.
// ---------------------------------------------------------------------------
__global__ __launch_bounds__(256) void gemm_2048_512(
  const float* __restrict__ A, const float* __restrict__ W, float* __restrict__ Co)
{
  __shared__ float As[32][68];
  __shared__ float Bs[32][64];
  int tid = threadIdx.x;
  int tx = tid & 15, ty = tid >> 4;
  int m0 = blockIdx.y*64, n0 = blockIdx.x*64;
  float acc[4][4];
  #pragma unroll
  for (int i=0;i<4;i++)
    #pragma unroll
    for (int j=0;j<4;j++) acc[i][j]=0.f;

  for (int k0 = 0; k0 < 512; k0 += 32){
    #pragma unroll
    for (int i = 0; i < 8; i++){
      int e = tid + i*256;
      int kk = e & 31, m = e >> 5;
      As[kk][m] = A[(size_t)(m0+m)*512 + k0 + kk];
    }
    #pragma unroll
    for (int i = 0; i < 8; i++){
      int e = tid + i*256;
      int n = e & 63, kk = e >> 6;
      Bs[kk][n] = W[(size_t)(k0+kk)*512 + n0 + n];
    }
    __syncthreads();
    #pragma unroll
    for (int kk = 0; kk < 32; kk++){
      float a4[4], b4[4];
      #pragma unroll
      for (int i=0;i<4;i++) a4[i] = As[kk][ty*4+i];
      #pragma unroll
      for (int j=0;j<4;j++) b4[j] = Bs[kk][tx*4+j];
      #pragma unroll
      for (int i=0;i<4;i++)
        #pragma unroll
        for (int j=0;j<4;j++) acc[i][j] += a4[i]*b4[j];
    }
    __syncthreads();
  }
  #pragma unroll
  for (int i=0;i<4;i++)
    #pragma unroll
    for (int j=0;j<4;j++)
      Co[(size_t)(m0+ty*4+i)*512 + n0 + tx*4 + j] = acc[i][j];
}

// ---------------------------------------------------------------------------
// K1b: kk = normalize_per_head(k * k_k)
// ---------------------------------------------------------------------------
__global__ __launch_bounds__(512) void k_kk(
  const float* __restrict__ kg, const float* __restrict__ k_k,
  float* __restrict__ kkg)
{
  int bt = blockIdx.x, tid = threadIdx.x;
  float v = kg[(size_t)bt*CC + tid]*k_k[tid];
  float ss = wsum(v*v);
  float nrm = fmaxf(sqrtf(ss), 1e-12f);
  kkg[(size_t)bt*CC + tid] = v/nrm;
}

// ---------------------------------------------------------------------------
// K2: per (bq,t,c): decay w, k_final, b_vec = kk*a.  4 rows per block.
// ---------------------------------------------------------------------------
__global__ __launch_bounds__(256) void k_wkb(
  const float* __restrict__ Pw, const float* __restrict__ Pa,
  const float* __restrict__ Qw, const float* __restrict__ Qa,
  const float* __restrict__ w2, const float* __restrict__ a2,
  const float* __restrict__ w0, const float* __restrict__ a0,
  const float* __restrict__ k_a, const float* __restrict__ kg,
  const float* __restrict__ kkg,
  float* __restrict__ wS, float* __restrict__ kS, float* __restrict__ bS)
{
  int bqt0 = blockIdx.x*4;           // 4 consecutive t within one bq
  int bq = bqt0 >> 9, t0 = bqt0 & (TT-1), b = bq >> 3;
  int tid = threadIdx.x;
  __shared__ float sth[4][32], sal[4][32];
  {
    int g = (tid >> 5) & 3, d = tid & 31;
    int pidx = ((b << 9) | (t0 + g))*32 + d;
    if (tid < 128) sth[g][d] = tanhf(Pw[pidx] + Qw[bq*32 + d]);
    else           sal[g][d] = Pa[pidx] + Qa[bq*32 + d];
  }
  __syncthreads();
  #pragma unroll
  for (int cc = 0; cc < 2; cc++){
    int c = tid + cc*256;
    float wreg[32], areg[32];
    #pragma unroll
    for (int d = 0; d < 32; d++){ wreg[d] = w2[d*CC + c]; areg[d] = a2[d*CC + c]; }
    float w0c = w0[c], a0c = a0[c], kac = k_a[c];
    #pragma unroll
    for (int g = 0; g < 4; g++){
      float wa = 0.f, aa = 0.f;
      #pragma unroll
      for (int d = 0; d < 32; d++){
        wa = fmaf(sth[g][d], wreg[d], wa);
        aa = fmaf(sal[g][d], areg[d], aa);
      }
      float a_sig = sigm(a0c + aa);
      float wdec  = __expf(-0.60653066f * sigm(w0c + wa));
      size_t bt = (size_t)((b << 9) | (t0 + g));
      size_t o  = (size_t)(bqt0 + g)*CC + c;
      float kvv = kg[bt*CC + c];
      float kkv = kkg[bt*CC + c];
      wS[o] = wdec;
      kS[o] = kvv*(1.f + (a_sig - 1.f)*kac);
      bS[o] = kkv*a_sig;
    }
  }
}

// ---------------------------------------------------------------------------
// K3: BACKWARD vector scan.  Only the final timestep's output survives the
// reference (xo[:, -1, :]), and the recurrence is linear:
//   S_t = S_{t-1} (diag(w_t) + a_t b_t^T) + v_t k_t^T,   a_t = -kk_t.
// So out = S_{T-1} r = sum_s v_s * (k_s . g_s)  with
//   g_{T-1} = r,   g_{s-1} = M_s g_s = w_s*g_s - kk_s*(b_s . g_s).
// This replaces the O(N^2) forward state update with O(N) per step:
// ONE wave per (bq,h), lane = channel; per step 2 dot-reductions + 2 fma
// passes.  Memory-bound: same 7 streams, read in reverse, 8-deep register
// prefetch pipeline (56 loads in flight) to pace HBM with 256 waves.
// ---------------------------------------------------------------------------
__global__ __launch_bounds__(64) void k_scan(
  const float* __restrict__ wv, const float* __restrict__ kf,
  const float* __restrict__ bv, const float* __restrict__ kkg,
  const float* __restrict__ vpre, const float* __restrict__ svv,
  const float* __restrict__ vfirst,
  const float* __restrict__ rrow, const float* __restrict__ grow,
  const float* __restrict__ r_k, const float* __restrict__ ln_w,
  const float* __restrict__ ln_b, float* __restrict__ xo)
{
  int blk = blockIdx.x; int bq = blk >> 3, h = blk & 7, b = bq >> 3;
  int lane = threadIdx.x & 63;
  size_t cb_bq = (size_t)bq*TT*CC + h*NN;
  size_t cb_b  = (size_t)b*TT*CC + h*NN;

  const float* pw  = wv     + cb_bq + lane;
  const float* pk  = kf     + cb_bq + lane;
  const float* pb  = bv     + cb_bq + lane;
  const float* pa  = kkg    + cb_b  + lane;
  const float* pvp = vpre   + cb_b  + lane;
  const float* psv = svv    + cb_b  + lane;
  const float* pvf = vfirst + cb_bq + lane;

  float g   = rrow[(size_t)bq*CC + h*NN + lane];   // g_{T-1} = r
  float out = 0.f;

  constexpr int D = 8;                 // prefetch depth (steps)
  float fw[D], fk[D], fb[D], fa[D], fp[D], fs[D], fv[D];
  #pragma unroll
  for (int d = 0; d < D; ++d){
    size_t o = (size_t)(TT-1-d)*CC;
    fw[d]=pw[o]; fk[d]=pk[o]; fb[d]=pb[o]; fa[d]=pa[o];
    fp[d]=pvp[o]; fs[d]=psv[o]; fv[d]=pvf[o];
  }

  #pragma unroll 1
  for (int ob = 0; ob < TT/D; ++ob){
    int sbase = TT-1 - ob*D;
    #pragma unroll
    for (int d = 0; d < D; ++d){
      int s = sbase - d;
      float wj=fw[d], kj=fk[d], bj=fb[d], aj=fa[d];
      float vj = fp[d] + (fv[d]-fp[d])*fs[d];
      // prefetch step s-D into slot d (clamped; duplicate loads harmless)
      int sp = s - D; sp = sp < 0 ? 0 : sp;
      size_t o = (size_t)sp*CC;
      fw[d]=pw[o]; fk[d]=pk[o]; fb[d]=pb[o]; fa[d]=pa[o];
      fp[d]=pvp[o]; fs[d]=psv[o]; fv[d]=pvf[o];
      // two dot products vs g (full-wave broadcast reduce)
      float red[2];
      red[0] = kj*g;                    // k_s . g_s
      red[1] = bj*g;                    // b_s . g_s
      rowsum64_batch<2>(red);
      out = fmaf(red[0], vj, out);      // out += (k.g) * v
      g   = fmaf(wj, g, -(aj*red[1]));  // g = w*g - kk*(b.g)
    }
  }

  // epilogue: groupnorm over head + rk*v term + gate (per-lane channel)
  {
    float mean = wsum(out) * (1.f/NN);
    float dv = out - mean;
    float var = wsum(dv*dv) * (1.f/NN);
    float yn = dv * rsqrtf(var + 6.4e-4f);   // GN_EPS = 1e-5*64
    int c = h*NN + lane;
    float y2 = yn * ln_w[c] + ln_b[c];
    size_t oT = (size_t)(TT-1)*CC;
    float kl = pk[oT];
    float rl = rrow[(size_t)bq*CC + c];
    float rk = wsum(rl*kl*r_k[c]);
    float vp_ = pvp[oT], sv_ = psv[oT], vf_ = pvf[oT];
    float v_i = vp_ + (vf_ - vp_)*sv_;       // v_{T-1}
    float res = (y2 + rk*v_i) * grow[(size_t)bq*CC + c];
    xo[bq*CC + c] = res;
  }
}

// ---------------------------------------------------------------------------
// K4: out[bq,co] = xo[bq,:] @ Wo[:,co]
// ---------------------------------------------------------------------------
__global__ __launch_bounds__(256) void k_out(
  const float* __restrict__ xo, const float* __restrict__ Wo,
  float* __restrict__ outp)
{
  int bq = blockIdx.y; int co0 = blockIdx.x*64;
  int tid = threadIdx.x, tx = tid & 63, ty = tid >> 6;
  __shared__ float row[CC];
  __shared__ float red[4][64];
  row[tid]     = xo[bq*CC + tid];
  row[tid+256] = xo[bq*CC + tid + 256];
  __syncthreads();
  float p = 0.f;
  for (int i = 0; i < 128; i++){
    int c = ty*128 + i;
    p = fmaf(row[c], Wo[(size_t)c*CC + co0 + tx], p);
  }
  red[ty][tx] = p;
  __syncthreads();
  if (ty == 0)
    outp[bq*CC + co0 + tx] = (red[0][tx]+red[1][tx])+(red[2][tx]+red[3][tx]);
}

// ---------------------------------------------------------------------------
extern "C" void kernel_launch(void* const* d_in, const int* in_sizes, int n_in,
                              void* d_out, int out_size, void* d_ws, size_t ws_size,
                              hipStream_t stream)
{
  const float* q   = (const float*)d_in[0];
  const float* kv  = (const float*)d_in[1];
  const float* vf  = (const float*)d_in[2];
  const float* x_r = (const float*)d_in[3];
  const float* x_w = (const float*)d_in[4];
  const float* x_k = (const float*)d_in[5];
  const float* x_v = (const float*)d_in[6];
  const float* x_a = (const float*)d_in[7];
  const float* x_g = (const float*)d_in[8];
  const float* w0  = (const float*)d_in[9];
  const float* w1  = (const float*)d_in[10];
  const float* w2  = (const float*)d_in[11];
  const float* a0  = (const float*)d_in[12];
  const float* a1  = (const float*)d_in[13];
  const float* a2  = (const float*)d_in[14];
  const float* v0  = (const float*)d_in[15];
  const float* v1  = (const float*)d_in[16];
  const float* v2  = (const float*)d_in[17];
  const float* g1  = (const float*)d_in[18];
  const float* g2  = (const float*)d_in[19];
  const float* k_k = (const float*)d_in[20];
  const float* k_a = (const float*)d_in[21];
  const float* r_k = (const float*)d_in[22];
  const float* Wr  = (const float*)d_in[23];
  const float* Wk  = (const float*)d_in[24];
  const float* Wv  = (const float*)d_in[25];
  const float* Wo  = (const float*)d_in[26];
  const float* lnw = (const float*)d_in[27];
  const float* lnb = (const float*)d_in[28];
  float* outp = (float*)d_out;
  float* ws = (float*)d_ws;

  // workspace layout (floats)
  float* xk = ws + 0;         // 4*512*512
  float* xv = ws + 1048576;
  float* kg = ws + 2097152;   // k
  float* vp = ws + 3145728;   // v_pre
  float* sv = ws + 4194304;   // sigmoid lerp factor
  float* kk = ws + 5242880;   // normalized kk
  float* Pw = ws + 6291456;   // 4*512*32
  float* Pa = ws + 6356992;
  float* Qw = ws + 6422528;   // 32*32
  float* Qa = ws + 6423552;
  float* HV = ws + 6424576;   // 4*512*32
  float* rr = ws + 7473152;   // 32*512
  float* gr = ws + 7489536;
  float* xo = ws + 7505920;
  float* wS = ws + 7522304;   // 32*512*512 decay
  float* kS = ws + 15910912;  // k_final
  float* bS = ws + 24299520;  // kk*a
  float* xrw = ws + 32688128; // 32*512
  float* ghw = ws + 32704512; // 32*96

  // v_first passthrough (tuple output #2)
  hipMemcpyAsync(outp + BQ*CC, vf,
                 (size_t)BQ*TT*CC*sizeof(float), hipMemcpyDeviceToDevice, stream);

  k_prep<<<32, 256, 0, stream>>>(q, kv, x_r, x_w, x_a, x_g, w1, a1, g1,
                                 Qw, Qa, ghw, xrw);
  k_rg<<<dim3(8, 32), 256, 0, stream>>>(xrw, ghw, Wr, g2, rr, gr);
  k_shift<<<1024, 256, 0, stream>>>(kv, x_k, x_v, xk, xv);
  gemm_2048_512<<<dim3(8, 32), 256, 0, stream>>>(xk, Wk, kg);
  gemm_2048_512<<<dim3(8, 32), 256, 0, stream>>>(xv, Wv, vp);
  k_pgemm<<<dim3(32, 3), 256, 0, stream>>>(kv, xv, x_w, x_a, w1, a1, v1,
                                           Pw, Pa, HV);
  k_sv<<<NB*TT, 256, 0, stream>>>(HV, v2, v0, sv);
  k_kk<<<NB*TT, 512, 0, stream>>>(kg, k_k, kk);
  k_wkb<<<BQ*TT/4, 256, 0, stream>>>(Pw, Pa, Qw, Qa, w2, a2, w0, a0, k_a,
                                     kg, kk, wS, kS, bS);
  k_scan<<<BQ*HH, 64, 0, stream>>>(wS, kS, bS, kk, vp, sv, vf, rr, gr, r_k,
                                   lnw, lnb, xo);
  k_out<<<dim3(8, 32), 256, 0, stream>>>(xo, Wo, outp);
}